// Round 5
// baseline (322.277 us; speedup 1.0000x reference)
//
#include <hip/hip_runtime.h>

// FlowNetC correlation, B=16 C=256 H=48 W=64, 21x21 displacements (stride 2, +/-20).
// out[b, i*21+j, h, w] = sum_c in1[b,c,h,w] * in2[b,c,h+2i-20,w+2j-20]  (zero OOB)
//
// v5: v4's banded-Gram MFMA, de-serialized. v4 was latency-bound (MfmaUtil 7%,
// VALU 6%, HBM 11%, occ 15%): 3 blocks/CU and TWO vmcnt-draining barriers per oy.
//  - grid x4: oy split into 4 chunks of <=6 -> 3072 blocks, launch_bounds(256,3)
//    -> 12 waves/CU of desynchronized blocks.
//  - oy processed in PAIRS sharing the A-load (1 A + 2 B loads, 2 MFMAs per
//    k-step; acc0/acc1 in regs). A read from L1 each k (plane is L1-resident)
//    instead of 64 VGPRs -> register room for deep load pipelining.
//  - ONE barrier per pair: scatter both D-tiles into a double-buffered LDS slab
//    ([par][j][stride 34] -> <=2-way bank use), __syncthreads, copy-out; the
//    copy-out stores drain at the NEXT pair's barrier, a full 48-load/32-MFMA
//    phase later.
// Fallback: v3 dot2 kernel if ws too small.

#define NB 16
#define NC 256
#define NH 48
#define NW 64
#define HW (NH * NW)
#define CHW (NC * NH * NW)
#define ND 21
#define NDISP (ND * ND)
#define CHK 6                       // oy chunk per block (4 chunks cover 21)

typedef __fp16 half2v __attribute__((ext_vector_type(2)));
typedef _Float16 f16x8 __attribute__((ext_vector_type(8)));
typedef float f32x16 __attribute__((ext_vector_type(16)));

__device__ __forceinline__ unsigned pk2(float lo, float hi) {
    half2v h = __builtin_amdgcn_cvt_pkrtz(lo, hi);
    return __builtin_bit_cast(unsigned, h);
}
__device__ __forceinline__ half2v uph(unsigned u) {
    return __builtin_bit_cast(half2v, u);
}

// ---------------- Kernel T: transpose + pack ----------------
// src [b][c 256][h][w 64] f32 -> dst [(b_local*48+h)*2+par][w' 32][c 256] f16
__global__ void transpose_pack(const float* __restrict__ in1,
                               const float* __restrict__ in2,
                               unsigned* __restrict__ t1,
                               unsigned* __restrict__ t2,
                               int b_base, int nwg48) {
    const int bx = blockIdx.x;
    const int which = (bx >= nwg48) ? 1 : 0;
    const int r = bx - which * nwg48;
    const int b_local = r / NH;
    const int h = r % NH;
    const float* src = (which ? in2 : in1) + (size_t)(b_base + b_local) * CHW + (size_t)h * NW;
    unsigned* dst = which ? t2 : t1;

    const int t = threadIdx.x;
    const int w = t & 63;
    const int wid = t >> 6;
    const int plane = (b_local * NH + h) * 2 + (w & 1);
    unsigned* dp = dst + (size_t)plane * 4096 + (size_t)(w >> 1) * 128;

    #pragma unroll 1
    for (int i = 0; i < 8; ++i) {
        const int c8 = wid * 8 + i;
        const float* s = src + (size_t)(c8 * 8) * HW + w;
        float v0 = s[0 * HW], v1 = s[1 * HW], v2 = s[2 * HW], v3 = s[3 * HW];
        float v4 = s[4 * HW], v5 = s[5 * HW], v6 = s[6 * HW], v7 = s[7 * HW];
        uint4 q = make_uint4(pk2(v0, v1), pk2(v2, v3), pk2(v4, v5), pk2(v6, v7));
        *(uint4*)(dp + c8 * 4) = q;
    }
}

// ---------------- Kernel 2: banded-Gram MFMA, oy-pair pipelined ----------------
// slab region per oy: [par 2][j 21][34] = 1428 floats; pair = 2856; dbuf = 5712.
__global__ __launch_bounds__(256, 3)
void corr_mfma(const unsigned* __restrict__ in1T, const unsigned* __restrict__ in2T,
               float* __restrict__ out, int b_base, int nbh) {
    __shared__ float slab[5712];

    const int t = threadIdx.x;
    const int lane = t & 63;
    const int wid = t >> 6;
    const int par = wid >> 1;
    const int nt = wid & 1;
    const int ln31 = lane & 31;
    const int kh = lane >> 5;

    const int bx = blockIdx.x;
    const int c0 = (bx & 3) * CHK;          // oy chunk start
    const int r = bx >> 2;
    const int cpx = nbh >> 3;               // nbh = bc*48, divisible by 8
    const int L = (r & 7) * cpx + (r >> 3); // XCD-chunked swizzle
    const int b_local = L / NH;
    const int h = L % NH;
    const int b = b_base + b_local;

    float* out_b = out + (size_t)b * NDISP * HW + (size_t)h * NW;

    // B-lane geometry: w2' = nt*32 - 16 + ln31 (parity-plane column), zero OOB
    const int w2p = nt * 32 - 16 + ln31;
    const bool bval = ((unsigned)w2p < 32u);
    const int w2c = bval ? w2p : 0;
    const uint4 z4 = make_uint4(0u, 0u, 0u, 0u);

    const int lo = (h >= 20) ? 0 : ((21 - h) >> 1);
    const int hi = min(20, (67 - h) >> 1);
    const int ce = min(c0 + CHK - 1, ND - 1);

    // zero slabs for OOB oy rows within this chunk
    #pragma unroll 1
    for (int oy = c0; oy <= ce; ++oy) {
        if (oy >= lo && oy <= hi) continue;
        #pragma unroll
        for (int s_ = 0; s_ < 6; ++s_) {
            int k_ = t + 256 * s_;
            if (k_ < ND * NW)
                out_b[(size_t)(oy * ND + (k_ >> 6)) * HW + (k_ & 63)] = 0.f;
        }
    }

    const int s = max(c0, lo), e = min(ce, hi);
    if (s > e) return;

    const unsigned* pa = in1T +
        ((size_t)((b_local * NH + h) * 2 + par)) * 4096 + (size_t)ln31 * 128 + kh * 4;

#define SCAT(region_, acc_)                                                   \
    do {                                                                      \
        _Pragma("unroll") for (int r_ = 0; r_ < 16; ++r_) {                   \
            const int m_ = (r_ & 3) + 8 * (r_ >> 2) + 4 * kh;                 \
            const int j_ = 32 * nt + ln31 - m_ - 6;                           \
            if ((unsigned)j_ < (unsigned)ND)                                  \
                (region_)[par * 714 + j_ * 34 + m_] = acc_[r_];               \
        }                                                                     \
    } while (0)

#define COPYOUT(oy_, region_)                                                 \
    do {                                                                      \
        _Pragma("unroll") for (int s_ = 0; s_ < 6; ++s_) {                    \
            int k_ = t + 256 * s_;                                            \
            if (k_ < ND * NW) {                                               \
                int j_ = k_ >> 6, w_ = k_ & 63;                               \
                out_b[(size_t)((oy_)*ND + j_) * HW + w_] =                    \
                    (region_)[(w_ & 1) * 714 + j_ * 34 + (w_ >> 1)];          \
            }                                                                 \
        }                                                                     \
    } while (0)

    int buf = 0;
    #pragma unroll 1
    for (int oy = s; oy <= e; oy += 2, buf ^= 1) {
        const int oyB = min(oy + 1, e);     // singleton tail duplicates (harmless)
        const unsigned* pb0 = in2T +
            ((size_t)((b_local * NH + (h + 2 * oy - 20)) * 2 + par)) * 4096 +
            (size_t)w2c * 128 + kh * 4;
        const unsigned* pb1 = in2T +
            ((size_t)((b_local * NH + (h + 2 * oyB - 20)) * 2 + par)) * 4096 +
            (size_t)w2c * 128 + kh * 4;

        f32x16 acc0, acc1;
        #pragma unroll
        for (int i = 0; i < 16; ++i) { acc0[i] = 0.f; acc1[i] = 0.f; }

        __builtin_amdgcn_s_setprio(1);
        #pragma unroll
        for (int kk = 0; kk < 16; ++kk) {
            const uint4 a = *(const uint4*)(pa + 8 * kk);
            const uint4 q0 = bval ? *(const uint4*)(pb0 + 8 * kk) : z4;
            const uint4 q1 = bval ? *(const uint4*)(pb1 + 8 * kk) : z4;
            acc0 = __builtin_amdgcn_mfma_f32_32x32x16_f16(
                __builtin_bit_cast(f16x8, a), __builtin_bit_cast(f16x8, q0), acc0, 0, 0, 0);
            acc1 = __builtin_amdgcn_mfma_f32_32x32x16_f16(
                __builtin_bit_cast(f16x8, a), __builtin_bit_cast(f16x8, q1), acc1, 0, 0, 0);
        }
        __builtin_amdgcn_s_setprio(0);

        float* sb = slab + buf * 2856;
        SCAT(sb, acc0);
        SCAT(sb + 1428, acc1);
        __syncthreads();
        COPYOUT(oy, sb);
        if (oyB != oy) COPYOUT(oyB, sb + 1428);
        // copy-out stores drain at the NEXT pair's barrier (other slab buffer),
        // overlapped with its 48 loads + 32 MFMAs.
    }
#undef SCAT
#undef COPYOUT
}

// ---------------- Fallback: v3 dot2 kernel ----------------
#define NCB 16
#define IN1_P 36
#define IN1_C2 (2 * IN1_P)
#define IN1_WORDS (128 * IN1_C2)
#define IN2_P 52
#define IN2_C2 (2 * IN2_P)
#define IN2_WAVE (8 * IN2_C2)
#define LDS_WORDS (IN1_WORDS + 4 * IN2_WAVE)

#if defined(__has_builtin)
#if __has_builtin(__builtin_amdgcn_fdot2)
#define HAVE_FDOT2 1
#endif
#endif
__device__ __forceinline__ float fdot2f(half2v a, half2v b, float c) {
#ifdef HAVE_FDOT2
    return __builtin_amdgcn_fdot2(a, b, c, false);
#else
    return c + (float)a.x * (float)b.x + (float)a.y * (float)b.y;
#endif
}
#define WW(u, m) uph(((m) & 1) ? wn[u][(m) >> 1].y : wn[u][(m) >> 1].x)

__global__ __launch_bounds__(256, 3)
void corr_kernel(const float* __restrict__ in1, const float* __restrict__ in2,
                 float* __restrict__ out) {
    __shared__ __align__(16) unsigned lds[LDS_WORDS];
    unsigned* in1_s = lds;
    const int t = threadIdx.x;
    const int lane = t & 63;
    const int wid = t >> 6;
    const int tw = lane & 7;
    const int oh = (lane >> 3) & 1;
    const int p = (lane >> 4) & 1;
    const int chalf = (lane >> 5) & 1;
    unsigned* in2w = lds + IN1_WORDS + wid * IN2_WAVE;
    const int bx = blockIdx.x;
    const int L = (bx & 7) * 96 + (bx >> 3);
    const int b = L / NH;
    const int h = L % NH;
    const float* in1_row = in1 + (size_t)b * CHW + (size_t)h * NW;
    for (int i = lane; i < IN2_WAVE; i += 64) in2w[i] = 0u;
    #pragma unroll 1
    for (int j = 0; j < 8; ++j) {
        const int task = t + 256 * j;
        const int c2 = task >> 4;
        const int c4 = task & 15;
        const float4 u0 = ((const float4*)(in1_row + (size_t)(2 * c2) * HW))[c4];
        const float4 u1 = ((const float4*)(in1_row + (size_t)(2 * c2 + 1) * HW))[c4];
        unsigned* d0 = &in1_s[c2 * IN1_C2 + 2 * c4];
        *(uint2*)&d0[0] = make_uint2(pk2(u0.x, u1.x), pk2(u0.z, u1.z));
        *(uint2*)&d0[IN1_P] = make_uint2(pk2(u0.y, u1.y), pk2(u0.w, u1.w));
    }
    __syncthreads();
    const int q = lane >> 4;
    const int col4 = lane & 15;
    const int lo = (h >= 20) ? 0 : ((21 - h) >> 1);
    const int hi = min(20, (67 - h) >> 1);
    const int nv = hi - lo + 1;
    const int rot = (wid + h) & 3;
    #pragma unroll 1
    for (int oy = rot; oy < ND; oy += 4) {
        if (oy >= lo && oy <= hi) continue;
        float* orow = out + ((size_t)(b * NDISP + oy * ND) * NH + h) * NW;
        #pragma unroll
        for (int o = 0; o < ND; ++o) orow[(size_t)o * HW + lane] = 0.f;
    }
    #pragma unroll 1
    for (int k = rot; k < nv; k += 4) {
        const int oyi = lo + k;
        const int row = h + 2 * oyi - 20;
        float* orow = out + ((size_t)(b * NDISP + oyi * ND) * NH + h) * NW;
        const float* in2_row = in2 + (size_t)b * CHW + (size_t)row * NW;
        float acc[11][4];
        #pragma unroll
        for (int ol = 0; ol < 11; ++ol)
            #pragma unroll
            for (int i = 0; i < 4; ++i) acc[ol][i] = 0.f;
        float4 pre[4];
        {
            const float* s0 = in2_row + (size_t)(2 * q) * HW;
            const float* s1 = in2_row + (size_t)(2 * (q + 4)) * HW;
            pre[0] = ((const float4*)s0)[col4];
            pre[1] = ((const float4*)(s0 + HW))[col4];
            pre[2] = ((const float4*)s1)[col4];
            pre[3] = ((const float4*)(s1 + HW))[col4];
        }
        #pragma unroll 1
        for (int cb = 0; cb < NCB; ++cb) {
            {
                unsigned* da = &in2w[q * IN2_C2 + 2 * col4 + 10];
                unsigned* db = &in2w[(q + 4) * IN2_C2 + 2 * col4 + 10];
                *(uint2*)&da[0] = make_uint2(pk2(pre[0].x, pre[1].x), pk2(pre[0].z, pre[1].z));
                *(uint2*)&da[IN2_P] = make_uint2(pk2(pre[0].y, pre[1].y), pk2(pre[0].w, pre[1].w));
                *(uint2*)&db[0] = make_uint2(pk2(pre[2].x, pre[3].x), pk2(pre[2].z, pre[3].z));
                *(uint2*)&db[IN2_P] = make_uint2(pk2(pre[2].y, pre[3].y), pk2(pre[2].w, pre[3].w));
            }
            if (cb + 1 < NCB) {
                const float* srcn = in2_row + (size_t)((cb + 1) * 16) * HW;
                const float* s0 = srcn + (size_t)(2 * q) * HW;
                const float* s1 = srcn + (size_t)(2 * (q + 4)) * HW;
                pre[0] = ((const float4*)s0)[col4];
                pre[1] = ((const float4*)(s0 + HW))[col4];
                pre[2] = ((const float4*)s1)[col4];
                pre[3] = ((const float4*)(s1 + HW))[col4];
            }
            uint4 avv[4];
            uint2 wn[4][7];
            {
                const unsigned* base1 = &in1_s[(cb * 8 + chalf) * IN1_C2 + p * IN1_P + 4 * tw];
                const unsigned* base2 = &in2w[chalf * IN2_C2 + p * IN2_P + 4 * tw + 10 * oh];
                #pragma unroll
                for (int u = 0; u < 4; ++u) {
                    avv[u] = *(const uint4*)(base1 + (size_t)(2 * u) * IN1_C2);
                    #pragma unroll
                    for (int jj = 0; jj < 7; ++jj)
                        wn[u][jj] = *(const uint2*)(base2 + (size_t)(2 * u) * IN2_C2 + 2 * jj);
                }
            }
            #pragma unroll
            for (int u = 0; u < 4; ++u) {
                const half2v a0 = uph(avv[u].x), a1 = uph(avv[u].y);
                const half2v a2 = uph(avv[u].z), a3 = uph(avv[u].w);
                #pragma unroll
                for (int ol = 0; ol < 11; ++ol) {
                    acc[ol][0] = fdot2f(a0, WW(u, ol + 0), acc[ol][0]);
                    acc[ol][1] = fdot2f(a1, WW(u, ol + 1), acc[ol][1]);
                    acc[ol][2] = fdot2f(a2, WW(u, ol + 2), acc[ol][2]);
                    acc[ol][3] = fdot2f(a3, WW(u, ol + 3), acc[ol][3]);
                }
            }
        }
        #pragma unroll
        for (int ol = 0; ol < 11; ++ol)
            #pragma unroll
            for (int i = 0; i < 4; ++i) {
                float v = acc[ol][i];
                v += __shfl_xor(v, 32);
                acc[ol][i] = v;
            }
        if (chalf == 0) {
            #pragma unroll
            for (int ol = 0; ol < 11; ++ol) {
                if (oh == 1 && ol == 0) continue;
                const int og = 10 * oh + ol;
                #pragma unroll
                for (int i = 0; i < 4; ++i)
                    orow[(size_t)og * HW + (p + 8 * tw + 2 * i)] = acc[ol][i];
            }
        }
    }
}

// ---------------- host ----------------
extern "C" void kernel_launch(void* const* d_in, const int* in_sizes, int n_in,
                              void* d_out, int out_size, void* d_ws, size_t ws_size,
                              hipStream_t stream) {
    const float* in1 = (const float*)d_in[0];
    const float* in2 = (const float*)d_in[1];
    float* out = (float*)d_out;

    const size_t per_b = 1572864;  // 48*2*32*256*2 bytes
    int bc = 0;
    const int cands[5] = {16, 8, 4, 2, 1};
    for (int i = 0; i < 5; ++i) {
        if ((size_t)cands[i] * 2 * per_b <= ws_size) { bc = cands[i]; break; }
    }
    if (bc == 0) {
        corr_kernel<<<dim3(NB * NH), dim3(256), 0, stream>>>(in1, in2, out);
        return;
    }
    unsigned* t1 = (unsigned*)d_ws;
    unsigned* t2 = t1 + (size_t)bc * NH * 2 * 4096;
    const int nwg48 = bc * NH;
    for (int b0 = 0; b0 < NB; b0 += bc) {
        transpose_pack<<<dim3(2 * nwg48), dim3(256), 0, stream>>>(in1, in2, t1, t2, b0, nwg48);
        corr_mfma<<<dim3(nwg48 * 4), dim3(256), 0, stream>>>(t1, t2, out, b0, nwg48);
    }
}

// Round 6
// 167.204 us; speedup vs baseline: 1.9274x; 1.9274x over previous
//
#include <hip/hip_runtime.h>

// FlowNetC correlation, B=16 C=256 H=48 W=64, 21x21 displacements (stride 2, +/-20).
// out[b, i*21+j, h, w] = sum_c in1[b,c,h,w] * in2[b,c,h+2i-20,w+2j-20]  (zero OOB)
//
// v6 = v4 locality + v5 pipelining:
//  - block = (b,h), FULL oy range (768 blocks) -> B rows read once per block,
//    A read once into 64 VGPRs (v5's oy-chunking + A-from-global blew FETCH to
//    227MB / L2 thrash).
//  - oy PAIRS share the A-frags: 2 accs, one barrier per pair; double-buffered
//    LDS slab so copy-out stores drain at the NEXT pair's barrier (a full
//    32-MFMA phase later).
//  - hand 2-deep B software pipeline (b cur/next regs) keeps VGPR ~130 under
//    the launch_bounds(256,3) cap of 168 (v4's (256,2) capped residency at 2
//    blocks/CU -> 15% occupancy; 768 blocks need 3/CU).
// Fallback: v3 dot2 kernel if ws too small.

#define NB 16
#define NC 256
#define NH 48
#define NW 64
#define HW (NH * NW)
#define CHW (NC * NH * NW)
#define ND 21
#define NDISP (ND * ND)

typedef __fp16 half2v __attribute__((ext_vector_type(2)));
typedef _Float16 f16x8 __attribute__((ext_vector_type(8)));
typedef float f32x16 __attribute__((ext_vector_type(16)));

__device__ __forceinline__ unsigned pk2(float lo, float hi) {
    half2v h = __builtin_amdgcn_cvt_pkrtz(lo, hi);
    return __builtin_bit_cast(unsigned, h);
}
__device__ __forceinline__ half2v uph(unsigned u) {
    return __builtin_bit_cast(half2v, u);
}

// ---------------- Kernel T: transpose + pack ----------------
// src [b][c 256][h][w 64] f32 -> dst [(b_local*48+h)*2+par][w' 32][c 256] f16
__global__ void transpose_pack(const float* __restrict__ in1,
                               const float* __restrict__ in2,
                               unsigned* __restrict__ t1,
                               unsigned* __restrict__ t2,
                               int b_base, int nwg48) {
    const int bx = blockIdx.x;
    const int which = (bx >= nwg48) ? 1 : 0;
    const int r = bx - which * nwg48;
    const int b_local = r / NH;
    const int h = r % NH;
    const float* src = (which ? in2 : in1) + (size_t)(b_base + b_local) * CHW + (size_t)h * NW;
    unsigned* dst = which ? t2 : t1;

    const int t = threadIdx.x;
    const int w = t & 63;
    const int wid = t >> 6;
    const int plane = (b_local * NH + h) * 2 + (w & 1);
    unsigned* dp = dst + (size_t)plane * 4096 + (size_t)(w >> 1) * 128;

    #pragma unroll 1
    for (int i = 0; i < 8; ++i) {
        const int c8 = wid * 8 + i;
        const float* s = src + (size_t)(c8 * 8) * HW + w;
        float v0 = s[0 * HW], v1 = s[1 * HW], v2 = s[2 * HW], v3 = s[3 * HW];
        float v4 = s[4 * HW], v5 = s[5 * HW], v6 = s[6 * HW], v7 = s[7 * HW];
        uint4 q = make_uint4(pk2(v0, v1), pk2(v2, v3), pk2(v4, v5), pk2(v6, v7));
        *(uint4*)(dp + c8 * 4) = q;
    }
}

// ---------------- Kernel 2: banded-Gram MFMA ----------------
// slab region per oy: [par 2][j 21][34] = 1428 floats; pair = 2856; dbuf = 5712.
__global__ __launch_bounds__(256, 3)
void corr_mfma(const unsigned* __restrict__ in1T, const unsigned* __restrict__ in2T,
               float* __restrict__ out, int b_base, int nbh) {
    __shared__ float slab[5712];

    const int t = threadIdx.x;
    const int lane = t & 63;
    const int wid = t >> 6;
    const int par = wid >> 1;
    const int nt = wid & 1;
    const int ln31 = lane & 31;
    const int kh = lane >> 5;

    const int bx = blockIdx.x;
    const int cpx = nbh >> 3;               // nbh = bc*48, divisible by 8
    const int L = (bx & 7) * cpx + (bx >> 3);
    const int b_local = L / NH;
    const int h = L % NH;
    const int b = b_base + b_local;

    float* out_b = out + (size_t)b * NDISP * HW + (size_t)h * NW;

    // B-lane geometry: w2' = nt*32 - 16 + ln31 (parity-plane column), zero OOB
    const int w2p = nt * 32 - 16 + ln31;
    const bool bval = ((unsigned)w2p < 32u);
    const int w2c = bval ? w2p : 0;
    const uint4 z4 = make_uint4(0u, 0u, 0u, 0u);

    const int lo = (h >= 20) ? 0 : ((21 - h) >> 1);
    const int hi = min(20, (67 - h) >> 1);

    // zero slabs for OOB oy rows
    #pragma unroll 1
    for (int oy = 0; oy < ND; ++oy) {
        if (oy >= lo && oy <= hi) continue;
        #pragma unroll
        for (int s_ = 0; s_ < 6; ++s_) {
            int k_ = t + 256 * s_;
            if (k_ < ND * NW)
                out_b[(size_t)(oy * ND + (k_ >> 6)) * HW + (k_ & 63)] = 0.f;
        }
    }

    // ---- A-frags to registers (once per block) ----
    uint4 av[16];
    {
        const unsigned* pa = in1T +
            ((size_t)((b_local * NH + h) * 2 + par)) * 4096 +
            (size_t)ln31 * 128 + kh * 4;
        #pragma unroll
        for (int kk = 0; kk < 16; ++kk)
            av[kk] = *(const uint4*)(pa + 8 * kk);
    }

#define SCAT(region_, acc_)                                                   \
    do {                                                                      \
        _Pragma("unroll") for (int r_ = 0; r_ < 16; ++r_) {                   \
            const int m_ = (r_ & 3) + 8 * (r_ >> 2) + 4 * kh;                 \
            const int j_ = 32 * nt + ln31 - m_ - 6;                           \
            if ((unsigned)j_ < (unsigned)ND)                                  \
                (region_)[par * 714 + j_ * 34 + m_] = acc_[r_];               \
        }                                                                     \
    } while (0)

#define COPYOUT(oy_, region_)                                                 \
    do {                                                                      \
        _Pragma("unroll") for (int s_ = 0; s_ < 6; ++s_) {                    \
            int k_ = t + 256 * s_;                                            \
            if (k_ < ND * NW) {                                               \
                int j_ = k_ >> 6, w_ = k_ & 63;                               \
                out_b[(size_t)((oy_)*ND + j_) * HW + w_] =                    \
                    (region_)[(w_ & 1) * 714 + j_ * 34 + (w_ >> 1)];          \
            }                                                                 \
        }                                                                     \
    } while (0)

    const int s = lo, e = hi;
    int buf = 0;
    #pragma unroll 1
    for (int oy = s; oy <= e; oy += 2, buf ^= 1) {
        const int oyB = min(oy + 1, e);     // singleton tail duplicates (harmless)
        const unsigned* pb0 = in2T +
            ((size_t)((b_local * NH + (h + 2 * oy - 20)) * 2 + par)) * 4096 +
            (size_t)w2c * 128 + kh * 4;
        const unsigned* pb1 = in2T +
            ((size_t)((b_local * NH + (h + 2 * oyB - 20)) * 2 + par)) * 4096 +
            (size_t)w2c * 128 + kh * 4;

        f32x16 acc0, acc1;
        #pragma unroll
        for (int i = 0; i < 16; ++i) { acc0[i] = 0.f; acc1[i] = 0.f; }

        // 2-deep B software pipeline
        uint4 b0 = bval ? *(const uint4*)(pb0 + 0) : z4;
        uint4 b1 = bval ? *(const uint4*)(pb1 + 0) : z4;

        __builtin_amdgcn_s_setprio(1);
        #pragma unroll
        for (int kk = 0; kk < 16; ++kk) {
            uint4 n0 = z4, n1 = z4;
            if (kk < 15) {
                n0 = bval ? *(const uint4*)(pb0 + 8 * (kk + 1)) : z4;
                n1 = bval ? *(const uint4*)(pb1 + 8 * (kk + 1)) : z4;
            }
            acc0 = __builtin_amdgcn_mfma_f32_32x32x16_f16(
                __builtin_bit_cast(f16x8, av[kk]), __builtin_bit_cast(f16x8, b0), acc0, 0, 0, 0);
            acc1 = __builtin_amdgcn_mfma_f32_32x32x16_f16(
                __builtin_bit_cast(f16x8, av[kk]), __builtin_bit_cast(f16x8, b1), acc1, 0, 0, 0);
            b0 = n0; b1 = n1;
        }
        __builtin_amdgcn_s_setprio(0);

        float* sb = slab + buf * 2856;
        SCAT(sb, acc0);
        SCAT(sb + 1428, acc1);
        __syncthreads();
        COPYOUT(oy, sb);
        if (oyB != oy) COPYOUT(oyB, sb + 1428);
        // copy-out stores drain at the NEXT pair's barrier (other slab buffer),
        // overlapped with its 32 loads + 32 MFMAs.
    }
#undef SCAT
#undef COPYOUT
}

// ---------------- Fallback: v3 dot2 kernel ----------------
#define NCB 16
#define IN1_P 36
#define IN1_C2 (2 * IN1_P)
#define IN1_WORDS (128 * IN1_C2)
#define IN2_P 52
#define IN2_C2 (2 * IN2_P)
#define IN2_WAVE (8 * IN2_C2)
#define LDS_WORDS (IN1_WORDS + 4 * IN2_WAVE)

#if defined(__has_builtin)
#if __has_builtin(__builtin_amdgcn_fdot2)
#define HAVE_FDOT2 1
#endif
#endif
__device__ __forceinline__ float fdot2f(half2v a, half2v b, float c) {
#ifdef HAVE_FDOT2
    return __builtin_amdgcn_fdot2(a, b, c, false);
#else
    return c + (float)a.x * (float)b.x + (float)a.y * (float)b.y;
#endif
}
#define WW(u, m) uph(((m) & 1) ? wn[u][(m) >> 1].y : wn[u][(m) >> 1].x)

__global__ __launch_bounds__(256, 3)
void corr_kernel(const float* __restrict__ in1, const float* __restrict__ in2,
                 float* __restrict__ out) {
    __shared__ __align__(16) unsigned lds[LDS_WORDS];
    unsigned* in1_s = lds;
    const int t = threadIdx.x;
    const int lane = t & 63;
    const int wid = t >> 6;
    const int tw = lane & 7;
    const int oh = (lane >> 3) & 1;
    const int p = (lane >> 4) & 1;
    const int chalf = (lane >> 5) & 1;
    unsigned* in2w = lds + IN1_WORDS + wid * IN2_WAVE;
    const int bx = blockIdx.x;
    const int L = (bx & 7) * 96 + (bx >> 3);
    const int b = L / NH;
    const int h = L % NH;
    const float* in1_row = in1 + (size_t)b * CHW + (size_t)h * NW;
    for (int i = lane; i < IN2_WAVE; i += 64) in2w[i] = 0u;
    #pragma unroll 1
    for (int j = 0; j < 8; ++j) {
        const int task = t + 256 * j;
        const int c2 = task >> 4;
        const int c4 = task & 15;
        const float4 u0 = ((const float4*)(in1_row + (size_t)(2 * c2) * HW))[c4];
        const float4 u1 = ((const float4*)(in1_row + (size_t)(2 * c2 + 1) * HW))[c4];
        unsigned* d0 = &in1_s[c2 * IN1_C2 + 2 * c4];
        *(uint2*)&d0[0] = make_uint2(pk2(u0.x, u1.x), pk2(u0.z, u1.z));
        *(uint2*)&d0[IN1_P] = make_uint2(pk2(u0.y, u1.y), pk2(u0.w, u1.w));
    }
    __syncthreads();
    const int q = lane >> 4;
    const int col4 = lane & 15;
    const int lo = (h >= 20) ? 0 : ((21 - h) >> 1);
    const int hi = min(20, (67 - h) >> 1);
    const int nv = hi - lo + 1;
    const int rot = (wid + h) & 3;
    #pragma unroll 1
    for (int oy = rot; oy < ND; oy += 4) {
        if (oy >= lo && oy <= hi) continue;
        float* orow = out + ((size_t)(b * NDISP + oy * ND) * NH + h) * NW;
        #pragma unroll
        for (int o = 0; o < ND; ++o) orow[(size_t)o * HW + lane] = 0.f;
    }
    #pragma unroll 1
    for (int k = rot; k < nv; k += 4) {
        const int oyi = lo + k;
        const int row = h + 2 * oyi - 20;
        float* orow = out + ((size_t)(b * NDISP + oyi * ND) * NH + h) * NW;
        const float* in2_row = in2 + (size_t)b * CHW + (size_t)row * NW;
        float acc[11][4];
        #pragma unroll
        for (int ol = 0; ol < 11; ++ol)
            #pragma unroll
            for (int i = 0; i < 4; ++i) acc[ol][i] = 0.f;
        float4 pre[4];
        {
            const float* s0 = in2_row + (size_t)(2 * q) * HW;
            const float* s1 = in2_row + (size_t)(2 * (q + 4)) * HW;
            pre[0] = ((const float4*)s0)[col4];
            pre[1] = ((const float4*)(s0 + HW))[col4];
            pre[2] = ((const float4*)s1)[col4];
            pre[3] = ((const float4*)(s1 + HW))[col4];
        }
        #pragma unroll 1
        for (int cb = 0; cb < NCB; ++cb) {
            {
                unsigned* da = &in2w[q * IN2_C2 + 2 * col4 + 10];
                unsigned* db = &in2w[(q + 4) * IN2_C2 + 2 * col4 + 10];
                *(uint2*)&da[0] = make_uint2(pk2(pre[0].x, pre[1].x), pk2(pre[0].z, pre[1].z));
                *(uint2*)&da[IN2_P] = make_uint2(pk2(pre[0].y, pre[1].y), pk2(pre[0].w, pre[1].w));
                *(uint2*)&db[0] = make_uint2(pk2(pre[2].x, pre[3].x), pk2(pre[2].z, pre[3].z));
                *(uint2*)&db[IN2_P] = make_uint2(pk2(pre[2].y, pre[3].y), pk2(pre[2].w, pre[3].w));
            }
            if (cb + 1 < NCB) {
                const float* srcn = in2_row + (size_t)((cb + 1) * 16) * HW;
                const float* s0 = srcn + (size_t)(2 * q) * HW;
                const float* s1 = srcn + (size_t)(2 * (q + 4)) * HW;
                pre[0] = ((const float4*)s0)[col4];
                pre[1] = ((const float4*)(s0 + HW))[col4];
                pre[2] = ((const float4*)s1)[col4];
                pre[3] = ((const float4*)(s1 + HW))[col4];
            }
            uint4 avv[4];
            uint2 wn[4][7];
            {
                const unsigned* base1 = &in1_s[(cb * 8 + chalf) * IN1_C2 + p * IN1_P + 4 * tw];
                const unsigned* base2 = &in2w[chalf * IN2_C2 + p * IN2_P + 4 * tw + 10 * oh];
                #pragma unroll
                for (int u = 0; u < 4; ++u) {
                    avv[u] = *(const uint4*)(base1 + (size_t)(2 * u) * IN1_C2);
                    #pragma unroll
                    for (int jj = 0; jj < 7; ++jj)
                        wn[u][jj] = *(const uint2*)(base2 + (size_t)(2 * u) * IN2_C2 + 2 * jj);
                }
            }
            #pragma unroll
            for (int u = 0; u < 4; ++u) {
                const half2v a0 = uph(avv[u].x), a1 = uph(avv[u].y);
                const half2v a2 = uph(avv[u].z), a3 = uph(avv[u].w);
                #pragma unroll
                for (int ol = 0; ol < 11; ++ol) {
                    acc[ol][0] = fdot2f(a0, WW(u, ol + 0), acc[ol][0]);
                    acc[ol][1] = fdot2f(a1, WW(u, ol + 1), acc[ol][1]);
                    acc[ol][2] = fdot2f(a2, WW(u, ol + 2), acc[ol][2]);
                    acc[ol][3] = fdot2f(a3, WW(u, ol + 3), acc[ol][3]);
                }
            }
        }
        #pragma unroll
        for (int ol = 0; ol < 11; ++ol)
            #pragma unroll
            for (int i = 0; i < 4; ++i) {
                float v = acc[ol][i];
                v += __shfl_xor(v, 32);
                acc[ol][i] = v;
            }
        if (chalf == 0) {
            #pragma unroll
            for (int ol = 0; ol < 11; ++ol) {
                if (oh == 1 && ol == 0) continue;
                const int og = 10 * oh + ol;
                #pragma unroll
                for (int i = 0; i < 4; ++i)
                    orow[(size_t)og * HW + (p + 8 * tw + 2 * i)] = acc[ol][i];
            }
        }
    }
}

// ---------------- host ----------------
extern "C" void kernel_launch(void* const* d_in, const int* in_sizes, int n_in,
                              void* d_out, int out_size, void* d_ws, size_t ws_size,
                              hipStream_t stream) {
    const float* in1 = (const float*)d_in[0];
    const float* in2 = (const float*)d_in[1];
    float* out = (float*)d_out;

    const size_t per_b = 1572864;  // 48*2*32*256*2 bytes
    int bc = 0;
    const int cands[5] = {16, 8, 4, 2, 1};
    for (int i = 0; i < 5; ++i) {
        if ((size_t)cands[i] * 2 * per_b <= ws_size) { bc = cands[i]; break; }
    }
    if (bc == 0) {
        corr_kernel<<<dim3(NB * NH), dim3(256), 0, stream>>>(in1, in2, out);
        return;
    }
    unsigned* t1 = (unsigned*)d_ws;
    unsigned* t2 = t1 + (size_t)bc * NH * 2 * 4096;
    const int nwg48 = bc * NH;
    for (int b0 = 0; b0 < NB; b0 += bc) {
        transpose_pack<<<dim3(2 * nwg48), dim3(256), 0, stream>>>(in1, in2, t1, t2, b0, nwg48);
        corr_mfma<<<dim3(nwg48), dim3(256), 0, stream>>>(t1, t2, out, b0, nwg48);
    }
}

// Round 7
// 150.472 us; speedup vs baseline: 2.1418x; 1.1112x over previous
//
#include <hip/hip_runtime.h>

// FlowNetC correlation, B=16 C=256 H=48 W=64, 21x21 displacements (stride 2, +/-20).
// out[b, i*21+j, h, w] = sum_c in1[b,c,h,w] * in2[b,c,h+2i-20,w+2j-20]  (zero OOB)
//
// v7: kill k-loop latency exposure. v6 showed VGPR=76 -> compiler kept a 1-deep
// B pipeline + rematerialized A loads: ~32 serial ~300-cyc L2 stalls per pair
// (MfmaUtil 9%). Now: per oy, ALL 16 B-frags loaded into named regs upfront
// (straight-line unroll; counted vmcnt waits), then 16 back-to-back MFMAs.
// Single-oy iterations, slab 1428 x dbuf, one barrier/oy (prev copyout stores
// drain under next oy's loads+MFMA). transpose_pack rewritten with LDS staging
// so both global sides are dense cache lines.

#define NB 16
#define NC 256
#define NH 48
#define NW 64
#define HW (NH * NW)
#define CHW (NC * NH * NW)
#define ND 21
#define NDISP (ND * ND)

typedef __fp16 half2v __attribute__((ext_vector_type(2)));
typedef _Float16 f16x8 __attribute__((ext_vector_type(8)));
typedef float f32x16 __attribute__((ext_vector_type(16)));

__device__ __forceinline__ unsigned pk2(float lo, float hi) {
    half2v h = __builtin_amdgcn_cvt_pkrtz(lo, hi);
    return __builtin_bit_cast(unsigned, h);
}
__device__ __forceinline__ half2v uph(unsigned u) {
    return __builtin_bit_cast(half2v, u);
}

// ---------------- Kernel T: transpose + pack (LDS-staged) ----------------
// src [b][c 256][h][w 64] f32 -> dst [(b_local*48+h)*2+par][w' 32][c2 128] u32
// word(plane, w', c2) = pk2(src[2c2][2w'+par], src[2c2+1][2w'+par])
__global__ __launch_bounds__(256, 4)
void transpose_pack(const float* __restrict__ in1,
                    const float* __restrict__ in2,
                    unsigned* __restrict__ t1,
                    unsigned* __restrict__ t2,
                    int b_base, int nwg48) {
    __shared__ unsigned xs[64 * 129];        // [w 64][c2 128 +1 pad] -> conflict-free
    const int bx = blockIdx.x;
    const int which = (bx >= nwg48) ? 1 : 0;
    const int r = bx - which * nwg48;
    const int b_local = r / NH;
    const int h = r % NH;
    const float* src = (which ? in2 : in1) + (size_t)(b_base + b_local) * CHW + (size_t)h * NW;
    unsigned* dst = (which ? t2 : t1) + (size_t)((b_local * NH + h) * 2) * 4096;

    const int t = threadIdx.x;
    const int w = t & 63;
    const int c2b = t >> 6;                  // 0..3

    // stage: fully coalesced 256B row reads, pack c-pairs, LDS write stride 129
    #pragma unroll 8
    for (int it = 0; it < 32; ++it) {
        const int c2 = c2b * 32 + it;
        const float lo = src[(size_t)(2 * c2) * HW + w];
        const float hi = src[(size_t)(2 * c2 + 1) * HW + w];
        xs[w * 129 + c2] = pk2(lo, hi);
    }
    __syncthreads();
    // copyout: 128-word contiguous global runs per (par, w')
    #pragma unroll 8
    for (int it = 0; it < 32; ++it) {
        const int k = t + 256 * it;          // 0..8191
        const int c2 = k & 127;
        const int wp = k >> 7;               // par = wp>>5, w' = wp&31
        dst[(size_t)(wp >> 5) * 4096 + (size_t)(wp & 31) * 128 + c2] =
            xs[(2 * (wp & 31) + (wp >> 5)) * 129 + c2];
    }
}

// ---------------- Kernel 2: banded-Gram MFMA ----------------
// slab region per oy: [par 2][j 21][34] = 1428 floats; dbuf = 2856 (11.4 KB).
__global__ __launch_bounds__(256, 3)
void corr_mfma(const unsigned* __restrict__ in1T, const unsigned* __restrict__ in2T,
               float* __restrict__ out, int b_base, int nbh) {
    __shared__ float slab[2856];

    const int t = threadIdx.x;
    const int lane = t & 63;
    const int wid = t >> 6;
    const int par = wid >> 1;
    const int nt = wid & 1;
    const int ln31 = lane & 31;
    const int kh = lane >> 5;

    const int bx = blockIdx.x;
    const int cpx = nbh >> 3;               // nbh = bc*48, divisible by 8
    const int L = (bx & 7) * cpx + (bx >> 3);
    const int b_local = L / NH;
    const int h = L % NH;
    const int b = b_base + b_local;

    float* out_b = out + (size_t)b * NDISP * HW + (size_t)h * NW;

    // B-lane geometry: w2' = nt*32 - 16 + ln31 (parity-plane column), zero OOB
    const int w2p = nt * 32 - 16 + ln31;
    const bool bval = ((unsigned)w2p < 32u);
    const int w2c = bval ? w2p : 0;
    const uint4 z4 = make_uint4(0u, 0u, 0u, 0u);

    const int lo = (h >= 20) ? 0 : ((21 - h) >> 1);
    const int hi = min(20, (67 - h) >> 1);

    // zero slabs for OOB oy rows
    #pragma unroll 1
    for (int oy = 0; oy < ND; ++oy) {
        if (oy >= lo && oy <= hi) continue;
        #pragma unroll
        for (int s_ = 0; s_ < 6; ++s_) {
            int k_ = t + 256 * s_;
            if (k_ < ND * NW)
                out_b[(size_t)(oy * ND + (k_ >> 6)) * HW + (k_ & 63)] = 0.f;
        }
    }

    // ---- A-frags to registers (once per block; L1-hot if rematerialized) ----
    const unsigned* pa = in1T +
        ((size_t)((b_local * NH + h) * 2 + par)) * 4096 + (size_t)ln31 * 128 + kh * 4;
    uint4 av[16];
    #pragma unroll
    for (int kk = 0; kk < 16; ++kk) av[kk] = *(const uint4*)(pa + 8 * kk);

#define SCAT(region_, acc_)                                                   \
    do {                                                                      \
        _Pragma("unroll") for (int r_ = 0; r_ < 16; ++r_) {                   \
            const int m_ = (r_ & 3) + 8 * (r_ >> 2) + 4 * kh;                 \
            const int j_ = 32 * nt + ln31 - m_ - 6;                           \
            if ((unsigned)j_ < (unsigned)ND)                                  \
                (region_)[par * 714 + j_ * 34 + m_] = acc_[r_];               \
        }                                                                     \
    } while (0)

#define COPYOUT(oy_, region_)                                                 \
    do {                                                                      \
        _Pragma("unroll") for (int s_ = 0; s_ < 6; ++s_) {                    \
            int k_ = t + 256 * s_;                                            \
            if (k_ < ND * NW) {                                               \
                int j_ = k_ >> 6, w_ = k_ & 63;                               \
                out_b[(size_t)((oy_)*ND + j_) * HW + w_] =                    \
                    (region_)[(w_ & 1) * 714 + j_ * 34 + (w_ >> 1)];          \
            }                                                                 \
        }                                                                     \
    } while (0)

    int buf = 0;
    #pragma unroll 1
    for (int oy = lo; oy <= hi; ++oy, buf ^= 1) {
        const unsigned* pb = in2T +
            ((size_t)((b_local * NH + (h + 2 * oy - 20)) * 2 + par)) * 4096 +
            (size_t)w2c * 128 + kh * 4;

        // ALL 16 B-frags issued upfront -> one latency exposure per oy
        uint4 q[16];
        #pragma unroll
        for (int kk = 0; kk < 16; ++kk)
            q[kk] = bval ? *(const uint4*)(pb + 8 * kk) : z4;

        f32x16 acc;
        #pragma unroll
        for (int i = 0; i < 16; ++i) acc[i] = 0.f;

        __builtin_amdgcn_s_setprio(1);
        #pragma unroll
        for (int kk = 0; kk < 16; ++kk)
            acc = __builtin_amdgcn_mfma_f32_32x32x16_f16(
                __builtin_bit_cast(f16x8, av[kk]),
                __builtin_bit_cast(f16x8, q[kk]), acc, 0, 0, 0);
        __builtin_amdgcn_s_setprio(0);

        float* sb = slab + buf * 1428;
        SCAT(sb, acc);
        __syncthreads();              // scatter visible; prev copyout reads done
        COPYOUT(oy, sb);
        // copyout stores drain at the NEXT oy's barrier, hidden under its
        // 16 loads + 16 MFMAs (other slab buffer).
    }
#undef SCAT
#undef COPYOUT
}

// ---------------- Fallback: v3 dot2 kernel ----------------
#define NCB 16
#define IN1_P 36
#define IN1_C2 (2 * IN1_P)
#define IN1_WORDS (128 * IN1_C2)
#define IN2_P 52
#define IN2_C2 (2 * IN2_P)
#define IN2_WAVE (8 * IN2_C2)
#define LDS_WORDS (IN1_WORDS + 4 * IN2_WAVE)

#if defined(__has_builtin)
#if __has_builtin(__builtin_amdgcn_fdot2)
#define HAVE_FDOT2 1
#endif
#endif
__device__ __forceinline__ float fdot2f(half2v a, half2v b, float c) {
#ifdef HAVE_FDOT2
    return __builtin_amdgcn_fdot2(a, b, c, false);
#else
    return c + (float)a.x * (float)b.x + (float)a.y * (float)b.y;
#endif
}
#define WW(u, m) uph(((m) & 1) ? wn[u][(m) >> 1].y : wn[u][(m) >> 1].x)

__global__ __launch_bounds__(256, 3)
void corr_kernel(const float* __restrict__ in1, const float* __restrict__ in2,
                 float* __restrict__ out) {
    __shared__ __align__(16) unsigned lds[LDS_WORDS];
    unsigned* in1_s = lds;
    const int t = threadIdx.x;
    const int lane = t & 63;
    const int wid = t >> 6;
    const int tw = lane & 7;
    const int oh = (lane >> 3) & 1;
    const int p = (lane >> 4) & 1;
    const int chalf = (lane >> 5) & 1;
    unsigned* in2w = lds + IN1_WORDS + wid * IN2_WAVE;
    const int bx = blockIdx.x;
    const int L = (bx & 7) * 96 + (bx >> 3);
    const int b = L / NH;
    const int h = L % NH;
    const float* in1_row = in1 + (size_t)b * CHW + (size_t)h * NW;
    for (int i = lane; i < IN2_WAVE; i += 64) in2w[i] = 0u;
    #pragma unroll 1
    for (int j = 0; j < 8; ++j) {
        const int task = t + 256 * j;
        const int c2 = task >> 4;
        const int c4 = task & 15;
        const float4 u0 = ((const float4*)(in1_row + (size_t)(2 * c2) * HW))[c4];
        const float4 u1 = ((const float4*)(in1_row + (size_t)(2 * c2 + 1) * HW))[c4];
        unsigned* d0 = &in1_s[c2 * IN1_C2 + 2 * c4];
        *(uint2*)&d0[0] = make_uint2(pk2(u0.x, u1.x), pk2(u0.z, u1.z));
        *(uint2*)&d0[IN1_P] = make_uint2(pk2(u0.y, u1.y), pk2(u0.w, u1.w));
    }
    __syncthreads();
    const int q = lane >> 4;
    const int col4 = lane & 15;
    const int lo = (h >= 20) ? 0 : ((21 - h) >> 1);
    const int hi = min(20, (67 - h) >> 1);
    const int nv = hi - lo + 1;
    const int rot = (wid + h) & 3;
    #pragma unroll 1
    for (int oy = rot; oy < ND; oy += 4) {
        if (oy >= lo && oy <= hi) continue;
        float* orow = out + ((size_t)(b * NDISP + oy * ND) * NH + h) * NW;
        #pragma unroll
        for (int o = 0; o < ND; ++o) orow[(size_t)o * HW + lane] = 0.f;
    }
    #pragma unroll 1
    for (int k = rot; k < nv; k += 4) {
        const int oyi = lo + k;
        const int row = h + 2 * oyi - 20;
        float* orow = out + ((size_t)(b * NDISP + oyi * ND) * NH + h) * NW;
        const float* in2_row = in2 + (size_t)b * CHW + (size_t)row * NW;
        float acc[11][4];
        #pragma unroll
        for (int ol = 0; ol < 11; ++ol)
            #pragma unroll
            for (int i = 0; i < 4; ++i) acc[ol][i] = 0.f;
        float4 pre[4];
        {
            const float* s0 = in2_row + (size_t)(2 * q) * HW;
            const float* s1 = in2_row + (size_t)(2 * (q + 4)) * HW;
            pre[0] = ((const float4*)s0)[col4];
            pre[1] = ((const float4*)(s0 + HW))[col4];
            pre[2] = ((const float4*)s1)[col4];
            pre[3] = ((const float4*)(s1 + HW))[col4];
        }
        #pragma unroll 1
        for (int cb = 0; cb < NCB; ++cb) {
            {
                unsigned* da = &in2w[q * IN2_C2 + 2 * col4 + 10];
                unsigned* db = &in2w[(q + 4) * IN2_C2 + 2 * col4 + 10];
                *(uint2*)&da[0] = make_uint2(pk2(pre[0].x, pre[1].x), pk2(pre[0].z, pre[1].z));
                *(uint2*)&da[IN2_P] = make_uint2(pk2(pre[0].y, pre[1].y), pk2(pre[0].w, pre[1].w));
                *(uint2*)&db[0] = make_uint2(pk2(pre[2].x, pre[3].x), pk2(pre[2].z, pre[3].z));
                *(uint2*)&db[IN2_P] = make_uint2(pk2(pre[2].y, pre[3].y), pk2(pre[2].w, pre[3].w));
            }
            if (cb + 1 < NCB) {
                const float* srcn = in2_row + (size_t)((cb + 1) * 16) * HW;
                const float* s0 = srcn + (size_t)(2 * q) * HW;
                const float* s1 = srcn + (size_t)(2 * (q + 4)) * HW;
                pre[0] = ((const float4*)s0)[col4];
                pre[1] = ((const float4*)(s0 + HW))[col4];
                pre[2] = ((const float4*)s1)[col4];
                pre[3] = ((const float4*)(s1 + HW))[col4];
            }
            uint4 avv[4];
            uint2 wn[4][7];
            {
                const unsigned* base1 = &in1_s[(cb * 8 + chalf) * IN1_C2 + p * IN1_P + 4 * tw];
                const unsigned* base2 = &in2w[chalf * IN2_C2 + p * IN2_P + 4 * tw + 10 * oh];
                #pragma unroll
                for (int u = 0; u < 4; ++u) {
                    avv[u] = *(const uint4*)(base1 + (size_t)(2 * u) * IN1_C2);
                    #pragma unroll
                    for (int jj = 0; jj < 7; ++jj)
                        wn[u][jj] = *(const uint2*)(base2 + (size_t)(2 * u) * IN2_C2 + 2 * jj);
                }
            }
            #pragma unroll
            for (int u = 0; u < 4; ++u) {
                const half2v a0 = uph(avv[u].x), a1 = uph(avv[u].y);
                const half2v a2 = uph(avv[u].z), a3 = uph(avv[u].w);
                #pragma unroll
                for (int ol = 0; ol < 11; ++ol) {
                    acc[ol][0] = fdot2f(a0, WW(u, ol + 0), acc[ol][0]);
                    acc[ol][1] = fdot2f(a1, WW(u, ol + 1), acc[ol][1]);
                    acc[ol][2] = fdot2f(a2, WW(u, ol + 2), acc[ol][2]);
                    acc[ol][3] = fdot2f(a3, WW(u, ol + 3), acc[ol][3]);
                }
            }
        }
        #pragma unroll
        for (int ol = 0; ol < 11; ++ol)
            #pragma unroll
            for (int i = 0; i < 4; ++i) {
                float v = acc[ol][i];
                v += __shfl_xor(v, 32);
                acc[ol][i] = v;
            }
        if (chalf == 0) {
            #pragma unroll
            for (int ol = 0; ol < 11; ++ol) {
                if (oh == 1 && ol == 0) continue;
                const int og = 10 * oh + ol;
                #pragma unroll
                for (int i = 0; i < 4; ++i)
                    orow[(size_t)og * HW + (p + 8 * tw + 2 * i)] = acc[ol][i];
            }
        }
    }
}

// ---------------- host ----------------
extern "C" void kernel_launch(void* const* d_in, const int* in_sizes, int n_in,
                              void* d_out, int out_size, void* d_ws, size_t ws_size,
                              hipStream_t stream) {
    const float* in1 = (const float*)d_in[0];
    const float* in2 = (const float*)d_in[1];
    float* out = (float*)d_out;

    const size_t per_b = 1572864;  // 48*2*32*256*2 bytes
    int bc = 0;
    const int cands[5] = {16, 8, 4, 2, 1};
    for (int i = 0; i < 5; ++i) {
        if ((size_t)cands[i] * 2 * per_b <= ws_size) { bc = cands[i]; break; }
    }
    if (bc == 0) {
        corr_kernel<<<dim3(NB * NH), dim3(256), 0, stream>>>(in1, in2, out);
        return;
    }
    unsigned* t1 = (unsigned*)d_ws;
    unsigned* t2 = t1 + (size_t)bc * NH * 2 * 4096;
    const int nwg48 = bc * NH;
    for (int b0 = 0; b0 < NB; b0 += bc) {
        transpose_pack<<<dim3(2 * nwg48), dim3(256), 0, stream>>>(in1, in2, t1, t2, b0, nwg48);
        corr_mfma<<<dim3(nwg48), dim3(256), 0, stream>>>(t1, t2, out, b0, nwg48);
    }
}

// Round 8
// 129.825 us; speedup vs baseline: 2.4824x; 1.1590x over previous
//
#include <hip/hip_runtime.h>

// FlowNetC correlation, B=16 C=256 H=48 W=64, 21x21 displacements (stride 2, +/-20).
// out[b, i*21+j, h, w] = sum_c in1[b,c,h,w] * in2[b,c,h+2i-20,w+2j-20]  (zero OOB)
//
// v8: force the B-load pipeline by ROTATION. v6/v7 showed hipcc sinks any
// source-level load batch back to load->wait->mfma (VGPR 84 = A + 1-deep B).
// Now iteration oy's MFMAs consume q[] while the NEXT oy's 16 loads overwrite
// q[] afterwards (WAR blocks hoist; __syncthreads blocks sink) -> latency hides
// under scatter+barrier+copyout. OOB-lane zeroing moved to the CONSUME site
// (cndmask before mfma) so no VALU op touches loaded regs at issue time.

#define NB 16
#define NC 256
#define NH 48
#define NW 64
#define HW (NH * NW)
#define CHW (NC * NH * NW)
#define ND 21
#define NDISP (ND * ND)

typedef __fp16 half2v __attribute__((ext_vector_type(2)));
typedef _Float16 f16x8 __attribute__((ext_vector_type(8)));
typedef float f32x16 __attribute__((ext_vector_type(16)));

__device__ __forceinline__ unsigned pk2(float lo, float hi) {
    half2v h = __builtin_amdgcn_cvt_pkrtz(lo, hi);
    return __builtin_bit_cast(unsigned, h);
}
__device__ __forceinline__ half2v uph(unsigned u) {
    return __builtin_bit_cast(half2v, u);
}

// ---------------- Kernel T: transpose + pack (LDS-staged) ----------------
// src [b][c 256][h][w 64] f32 -> dst [(b_local*48+h)*2+par][w' 32][c2 128] u32
__global__ __launch_bounds__(256, 4)
void transpose_pack(const float* __restrict__ in1,
                    const float* __restrict__ in2,
                    unsigned* __restrict__ t1,
                    unsigned* __restrict__ t2,
                    int b_base, int nwg48) {
    __shared__ unsigned xs[64 * 129];        // [w 64][c2 128 +1 pad] -> conflict-free
    const int bx = blockIdx.x;
    const int which = (bx >= nwg48) ? 1 : 0;
    const int r = bx - which * nwg48;
    const int b_local = r / NH;
    const int h = r % NH;
    const float* src = (which ? in2 : in1) + (size_t)(b_base + b_local) * CHW + (size_t)h * NW;
    unsigned* dst = (which ? t2 : t1) + (size_t)((b_local * NH + h) * 2) * 4096;

    const int t = threadIdx.x;
    const int w = t & 63;
    const int c2b = t >> 6;                  // 0..3

    #pragma unroll 8
    for (int it = 0; it < 32; ++it) {
        const int c2 = c2b * 32 + it;
        const float lo = src[(size_t)(2 * c2) * HW + w];
        const float hi = src[(size_t)(2 * c2 + 1) * HW + w];
        xs[w * 129 + c2] = pk2(lo, hi);
    }
    __syncthreads();
    #pragma unroll 8
    for (int it = 0; it < 32; ++it) {
        const int k = t + 256 * it;          // 0..8191
        const int c2 = k & 127;
        const int wp = k >> 7;               // par = wp>>5, w' = wp&31
        dst[(size_t)(wp >> 5) * 4096 + (size_t)(wp & 31) * 128 + c2] =
            xs[(2 * (wp & 31) + (wp >> 5)) * 129 + c2];
    }
}

// ---------------- Kernel 2: banded-Gram MFMA, rotated B pipeline ----------------
// slab region per oy: [par 2][j 21][34] = 1428 floats; dbuf = 2856 (11.4 KB).
__global__ __launch_bounds__(256, 3)
void corr_mfma(const unsigned* __restrict__ in1T, const unsigned* __restrict__ in2T,
               float* __restrict__ out, int b_base, int nbh) {
    __shared__ float slab[2856];

    const int t = threadIdx.x;
    const int lane = t & 63;
    const int wid = t >> 6;
    const int par = wid >> 1;
    const int nt = wid & 1;
    const int ln31 = lane & 31;
    const int kh = lane >> 5;

    const int bx = blockIdx.x;
    const int cpx = nbh >> 3;               // nbh = bc*48, divisible by 8
    const int L = (bx & 7) * cpx + (bx >> 3);
    const int b_local = L / NH;
    const int h = L % NH;
    const int b = b_base + b_local;

    float* out_b = out + (size_t)b * NDISP * HW + (size_t)h * NW;

    // B-lane geometry: w2' = nt*32 - 16 + ln31 (parity-plane column), zero OOB
    const int w2p = nt * 32 - 16 + ln31;
    const bool bval = ((unsigned)w2p < 32u);
    const int w2c = bval ? w2p : 0;

    const int lo = (h >= 20) ? 0 : ((21 - h) >> 1);
    const int hi = min(20, (67 - h) >> 1);

    // zero slabs for OOB oy rows
    #pragma unroll 1
    for (int oy = 0; oy < ND; ++oy) {
        if (oy >= lo && oy <= hi) continue;
        #pragma unroll
        for (int s_ = 0; s_ < 6; ++s_) {
            int k_ = t + 256 * s_;
            if (k_ < ND * NW)
                out_b[(size_t)(oy * ND + (k_ >> 6)) * HW + (k_ & 63)] = 0.f;
        }
    }

    // ---- A-frags to registers (once per block) ----
    const unsigned* pa = in1T +
        ((size_t)((b_local * NH + h) * 2 + par)) * 4096 + (size_t)ln31 * 128 + kh * 4;
    uint4 av[16];
    #pragma unroll
    for (int kk = 0; kk < 16; ++kk) av[kk] = *(const uint4*)(pa + 8 * kk);

#define PB(oy_) (in2T + ((size_t)((b_local * NH + (h + 2 * (oy_) - 20)) * 2 + par)) * 4096 + \
                 (size_t)w2c * 128 + kh * 4)

#define SCAT(region_, acc_)                                                   \
    do {                                                                      \
        _Pragma("unroll") for (int r_ = 0; r_ < 16; ++r_) {                   \
            const int m_ = (r_ & 3) + 8 * (r_ >> 2) + 4 * kh;                 \
            const int j_ = 32 * nt + ln31 - m_ - 6;                           \
            if ((unsigned)j_ < (unsigned)ND)                                  \
                (region_)[par * 714 + j_ * 34 + m_] = acc_[r_];               \
        }                                                                     \
    } while (0)

#define COPYOUT(oy_, region_)                                                 \
    do {                                                                      \
        _Pragma("unroll") for (int s_ = 0; s_ < 6; ++s_) {                    \
            int k_ = t + 256 * s_;                                            \
            if (k_ < ND * NW) {                                               \
                int j_ = k_ >> 6, w_ = k_ & 63;                               \
                out_b[(size_t)((oy_)*ND + j_) * HW + w_] =                    \
                    (region_)[(w_ & 1) * 714 + j_ * 34 + (w_ >> 1)];          \
            }                                                                 \
        }                                                                     \
    } while (0)

    // prologue: issue oy=lo's 16 B-loads RAW (clamped address; zeroing at consume)
    uint4 q[16];
    {
        const unsigned* pb = PB(lo);
        #pragma unroll
        for (int kk = 0; kk < 16; ++kk) q[kk] = *(const uint4*)(pb + 8 * kk);
    }

    int buf = 0;
    #pragma unroll 1
    for (int oy = lo; oy <= hi; ++oy, buf ^= 1) {
        f32x16 acc;
        #pragma unroll
        for (int i = 0; i < 16; ++i) acc[i] = 0.f;

        // consume q[] (vmcnt waits land here, already satisfied in steady state)
        __builtin_amdgcn_s_setprio(1);
        #pragma unroll
        for (int kk = 0; kk < 16; ++kk) {
            uint4 qq;
            qq.x = bval ? q[kk].x : 0u;       // cndmask at consume site
            qq.y = bval ? q[kk].y : 0u;
            qq.z = bval ? q[kk].z : 0u;
            qq.w = bval ? q[kk].w : 0u;
            acc = __builtin_amdgcn_mfma_f32_32x32x16_f16(
                __builtin_bit_cast(f16x8, av[kk]),
                __builtin_bit_cast(f16x8, qq), acc, 0, 0, 0);
        }
        __builtin_amdgcn_s_setprio(0);

        // rotate: issue NEXT oy's loads into q (WAR blocks hoist above MFMAs;
        // the __syncthreads below blocks sinking) -> in flight across barrier,
        // hidden under SCAT + barrier + COPYOUT.
        if (oy + 1 <= hi) {
            const unsigned* pb = PB(oy + 1);
            #pragma unroll
            for (int kk = 0; kk < 16; ++kk) q[kk] = *(const uint4*)(pb + 8 * kk);
        }

        float* sb = slab + buf * 1428;
        SCAT(sb, acc);
        __syncthreads();              // drains lgkm only; global loads stay in flight
        COPYOUT(oy, sb);
    }
#undef SCAT
#undef COPYOUT
#undef PB
}

// ---------------- Fallback: v3 dot2 kernel ----------------
#define NCB 16
#define IN1_P 36
#define IN1_C2 (2 * IN1_P)
#define IN1_WORDS (128 * IN1_C2)
#define IN2_P 52
#define IN2_C2 (2 * IN2_P)
#define IN2_WAVE (8 * IN2_C2)
#define LDS_WORDS (IN1_WORDS + 4 * IN2_WAVE)

#if defined(__has_builtin)
#if __has_builtin(__builtin_amdgcn_fdot2)
#define HAVE_FDOT2 1
#endif
#endif
__device__ __forceinline__ float fdot2f(half2v a, half2v b, float c) {
#ifdef HAVE_FDOT2
    return __builtin_amdgcn_fdot2(a, b, c, false);
#else
    return c + (float)a.x * (float)b.x + (float)a.y * (float)b.y;
#endif
}
#define WW(u, m) uph(((m) & 1) ? wn[u][(m) >> 1].y : wn[u][(m) >> 1].x)

__global__ __launch_bounds__(256, 3)
void corr_kernel(const float* __restrict__ in1, const float* __restrict__ in2,
                 float* __restrict__ out) {
    __shared__ __align__(16) unsigned lds[LDS_WORDS];
    unsigned* in1_s = lds;
    const int t = threadIdx.x;
    const int lane = t & 63;
    const int wid = t >> 6;
    const int tw = lane & 7;
    const int oh = (lane >> 3) & 1;
    const int p = (lane >> 4) & 1;
    const int chalf = (lane >> 5) & 1;
    unsigned* in2w = lds + IN1_WORDS + wid * IN2_WAVE;
    const int bx = blockIdx.x;
    const int L = (bx & 7) * 96 + (bx >> 3);
    const int b = L / NH;
    const int h = L % NH;
    const float* in1_row = in1 + (size_t)b * CHW + (size_t)h * NW;
    for (int i = lane; i < IN2_WAVE; i += 64) in2w[i] = 0u;
    #pragma unroll 1
    for (int j = 0; j < 8; ++j) {
        const int task = t + 256 * j;
        const int c2 = task >> 4;
        const int c4 = task & 15;
        const float4 u0 = ((const float4*)(in1_row + (size_t)(2 * c2) * HW))[c4];
        const float4 u1 = ((const float4*)(in1_row + (size_t)(2 * c2 + 1) * HW))[c4];
        unsigned* d0 = &in1_s[c2 * IN1_C2 + 2 * c4];
        *(uint2*)&d0[0] = make_uint2(pk2(u0.x, u1.x), pk2(u0.z, u1.z));
        *(uint2*)&d0[IN1_P] = make_uint2(pk2(u0.y, u1.y), pk2(u0.w, u1.w));
    }
    __syncthreads();
    const int q = lane >> 4;
    const int col4 = lane & 15;
    const int lo = (h >= 20) ? 0 : ((21 - h) >> 1);
    const int hi = min(20, (67 - h) >> 1);
    const int nv = hi - lo + 1;
    const int rot = (wid + h) & 3;
    #pragma unroll 1
    for (int oy = rot; oy < ND; oy += 4) {
        if (oy >= lo && oy <= hi) continue;
        float* orow = out + ((size_t)(b * NDISP + oy * ND) * NH + h) * NW;
        #pragma unroll
        for (int o = 0; o < ND; ++o) orow[(size_t)o * HW + lane] = 0.f;
    }
    #pragma unroll 1
    for (int k = rot; k < nv; k += 4) {
        const int oyi = lo + k;
        const int row = h + 2 * oyi - 20;
        float* orow = out + ((size_t)(b * NDISP + oyi * ND) * NH + h) * NW;
        const float* in2_row = in2 + (size_t)b * CHW + (size_t)row * NW;
        float acc[11][4];
        #pragma unroll
        for (int ol = 0; ol < 11; ++ol)
            #pragma unroll
            for (int i = 0; i < 4; ++i) acc[ol][i] = 0.f;
        float4 pre[4];
        {
            const float* s0 = in2_row + (size_t)(2 * q) * HW;
            const float* s1 = in2_row + (size_t)(2 * (q + 4)) * HW;
            pre[0] = ((const float4*)s0)[col4];
            pre[1] = ((const float4*)(s0 + HW))[col4];
            pre[2] = ((const float4*)s1)[col4];
            pre[3] = ((const float4*)(s1 + HW))[col4];
        }
        #pragma unroll 1
        for (int cb = 0; cb < NCB; ++cb) {
            {
                unsigned* da = &in2w[q * IN2_C2 + 2 * col4 + 10];
                unsigned* db = &in2w[(q + 4) * IN2_C2 + 2 * col4 + 10];
                *(uint2*)&da[0] = make_uint2(pk2(pre[0].x, pre[1].x), pk2(pre[0].z, pre[1].z));
                *(uint2*)&da[IN2_P] = make_uint2(pk2(pre[0].y, pre[1].y), pk2(pre[0].w, pre[1].w));
                *(uint2*)&db[0] = make_uint2(pk2(pre[2].x, pre[3].x), pk2(pre[2].z, pre[3].z));
                *(uint2*)&db[IN2_P] = make_uint2(pk2(pre[2].y, pre[3].y), pk2(pre[2].w, pre[3].w));
            }
            if (cb + 1 < NCB) {
                const float* srcn = in2_row + (size_t)((cb + 1) * 16) * HW;
                const float* s0 = srcn + (size_t)(2 * q) * HW;
                const float* s1 = srcn + (size_t)(2 * (q + 4)) * HW;
                pre[0] = ((const float4*)s0)[col4];
                pre[1] = ((const float4*)(s0 + HW))[col4];
                pre[2] = ((const float4*)s1)[col4];
                pre[3] = ((const float4*)(s1 + HW))[col4];
            }
            uint4 avv[4];
            uint2 wn[4][7];
            {
                const unsigned* base1 = &in1_s[(cb * 8 + chalf) * IN1_C2 + p * IN1_P + 4 * tw];
                const unsigned* base2 = &in2w[chalf * IN2_C2 + p * IN2_P + 4 * tw + 10 * oh];
                #pragma unroll
                for (int u = 0; u < 4; ++u) {
                    avv[u] = *(const uint4*)(base1 + (size_t)(2 * u) * IN1_C2);
                    #pragma unroll
                    for (int jj = 0; jj < 7; ++jj)
                        wn[u][jj] = *(const uint2*)(base2 + (size_t)(2 * u) * IN2_C2 + 2 * jj);
                }
            }
            #pragma unroll
            for (int u = 0; u < 4; ++u) {
                const half2v a0 = uph(avv[u].x), a1 = uph(avv[u].y);
                const half2v a2 = uph(avv[u].z), a3 = uph(avv[u].w);
                #pragma unroll
                for (int ol = 0; ol < 11; ++ol) {
                    acc[ol][0] = fdot2f(a0, WW(u, ol + 0), acc[ol][0]);
                    acc[ol][1] = fdot2f(a1, WW(u, ol + 1), acc[ol][1]);
                    acc[ol][2] = fdot2f(a2, WW(u, ol + 2), acc[ol][2]);
                    acc[ol][3] = fdot2f(a3, WW(u, ol + 3), acc[ol][3]);
                }
            }
        }
        #pragma unroll
        for (int ol = 0; ol < 11; ++ol)
            #pragma unroll
            for (int i = 0; i < 4; ++i) {
                float v = acc[ol][i];
                v += __shfl_xor(v, 32);
                acc[ol][i] = v;
            }
        if (chalf == 0) {
            #pragma unroll
            for (int ol = 0; ol < 11; ++ol) {
                if (oh == 1 && ol == 0) continue;
                const int og = 10 * oh + ol;
                #pragma unroll
                for (int i = 0; i < 4; ++i)
                    orow[(size_t)og * HW + (p + 8 * tw + 2 * i)] = acc[ol][i];
            }
        }
    }
}

// ---------------- host ----------------
extern "C" void kernel_launch(void* const* d_in, const int* in_sizes, int n_in,
                              void* d_out, int out_size, void* d_ws, size_t ws_size,
                              hipStream_t stream) {
    const float* in1 = (const float*)d_in[0];
    const float* in2 = (const float*)d_in[1];
    float* out = (float*)d_out;

    const size_t per_b = 1572864;  // 48*2*32*256*2 bytes
    int bc = 0;
    const int cands[5] = {16, 8, 4, 2, 1};
    for (int i = 0; i < 5; ++i) {
        if ((size_t)cands[i] * 2 * per_b <= ws_size) { bc = cands[i]; break; }
    }
    if (bc == 0) {
        corr_kernel<<<dim3(NB * NH), dim3(256), 0, stream>>>(in1, in2, out);
        return;
    }
    unsigned* t1 = (unsigned*)d_ws;
    unsigned* t2 = t1 + (size_t)bc * NH * 2 * 4096;
    const int nwg48 = bc * NH;
    for (int b0 = 0; b0 < NB; b0 += bc) {
        transpose_pack<<<dim3(2 * nwg48), dim3(256), 0, stream>>>(in1, in2, t1, t2, b0, nwg48);
        corr_mfma<<<dim3(nwg48), dim3(256), 0, stream>>>(t1, t2, out, b0, nwg48);
    }
}